// Round 8
// baseline (577.177 us; speedup 1.0000x reference)
//
#include <hip/hip_runtime.h>

#define E_TOTAL   500000
#define NN        50000
#define ND        128
#define ED        128
#define HID       256
#define IND       384   /* 2*ND + ED */
#define EB        64    /* edges per block */
#define NBLOCKS   ((E_TOTAL + EB - 1) / EB)

typedef float  f32x4  __attribute__((ext_vector_type(4)));
typedef short  bf16x8 __attribute__((ext_vector_type(8)));

__device__ __forceinline__ unsigned short f2bf(float f) {
    unsigned int u = __float_as_uint(f);
    u += 0x7FFFu + ((u >> 16) & 1u);   // RNE
    return (unsigned short)(u >> 16);
}
__device__ __forceinline__ float bf2f(unsigned short h) {
    return __uint_as_float(((unsigned int)h) << 16);
}

// ---------------- prep: node features fp32 -> bf16 ----------------
__global__ void prep_nodes(const float* __restrict__ nf, unsigned short* __restrict__ nb) {
    int i = (blockIdx.x * blockDim.x + threadIdx.x) * 4;
    if (i >= NN * ND) return;
    float4 v = *(const float4*)(nf + i);
    ushort4 o;
    o.x = f2bf(v.x); o.y = f2bf(v.y); o.z = f2bf(v.z); o.w = f2bf(v.w);
    *(ushort4*)(nb + i) = o;
}

// ---------------- prep: both weights fp32 -> bf16 transposed ----------------
__global__ void prep_weights(const float* __restrict__ w1, const float* __restrict__ w2,
                             unsigned short* __restrict__ w1t, unsigned short* __restrict__ w2t) {
    int i = blockIdx.x * blockDim.x + threadIdx.x;
    if (i < IND * HID) {
        int k = i / HID, n = i % HID;
        w1t[n * IND + k] = f2bf(w1[i]);          // W1T[n][k] = W1[k][n]
    } else if (i < IND * HID + HID * ED) {
        int q = i - IND * HID;
        int k = q / ED, n = q % ED;
        w2t[n * HID + k] = f2bf(w2[q]);          // W2T[n][k] = W2[k][n]
    }
}

// ---------------- main fused kernel ----------------
// 64-edge tile, 512 threads (8 waves, 2D split: wm = row-half, wn = col-quarter).
// LDS 48 KB as three 16 KB blocks: Asrc|Adst|Aedge ([64][128] bf16, swizzled).
// After GEMM1 (+barrier), Hs[64][256] overlays Asrc+Adst; Aedge survives for
// the residual. Gather = raw bf16 node rows (256 B/side) -> 256 MB random
// traffic total (half of the P-table design), zero VALU convert in gather.
__global__ __launch_bounds__(512, 6)
void edge_mlp(const float* __restrict__ edgef,
              const int* __restrict__ eidx,
              const unsigned short* __restrict__ nodesb,
              const unsigned short* __restrict__ w1t,
              const unsigned short* __restrict__ w2t,
              const float* __restrict__ b1,
              const float* __restrict__ b2,
              float* __restrict__ out) {
    __shared__ unsigned short At[3 * EB * ND];        // 48 KB
    unsigned short* Asrc  = At;                       // [64][128]
    unsigned short* Adst  = At + EB * ND;             // [64][128]
    unsigned short* Aedge = At + 2 * EB * ND;         // [64][128]
    unsigned short* Hs    = At;                       // [64][256] overlay (32 KB)

    const int tid  = threadIdx.x;
    const int base = blockIdx.x * EB;
    const int lane = tid & 63;
    const int w    = tid >> 6;       // 0..7
    const int wm   = w >> 2;         // 0..1 row-half
    const int wn   = w & 3;          // 0..3 col-quarter
    const int l15  = lane & 15;
    const int lhi  = lane >> 4;      // 0..3
    const int* srcI = eidx;
    const int* dstI = eidx + E_TOTAL;

    // ---- stage node rows: Asrc[row] = nodes[src[row]], Adst[row] = nodes[dst[row]] ----
    #pragma unroll
    for (int it = 0; it < 4; ++it) {
        int item = tid + it * 512;            // 0..2047 = 64 rows x (16 src + 16 dst)
        int row = item >> 5, c32 = item & 31;
        int e = base + row;
        int el = e < E_TOTAL ? e : E_TOTAL - 1;
        int c    = (c32 < 16) ? c32 : c32 - 16;
        int node = (c32 < 16) ? srcI[el] : dstI[el];
        bf16x8 v = *(const bf16x8*)(nodesb + (size_t)node * ND + c * 8);
        unsigned short* dp = ((c32 < 16) ? Asrc : Adst) + row * ND + ((c * 8) ^ ((row & 7) * 8));
        *(bf16x8*)dp = v;
    }

    // ---- stage Aedge: 64x128 edge features f32 -> bf16 (coalesced, read ONCE) ----
    #pragma unroll
    for (int it = 0; it < 2; ++it) {
        int item = tid + it * 512;            // 0..1023 = 64 rows x 16 chunks
        int row = item >> 4, cc = item & 15;
        int e = base + row;
        int el = e < E_TOTAL ? e : E_TOTAL - 1;
        const float* p = edgef + (size_t)el * ED + cc * 8;
        float4 f0 = *(const float4*)p;
        float4 f1 = *(const float4*)(p + 4);
        bf16x8 val;
        val[0] = (short)f2bf(f0.x); val[1] = (short)f2bf(f0.y);
        val[2] = (short)f2bf(f0.z); val[3] = (short)f2bf(f0.w);
        val[4] = (short)f2bf(f1.x); val[5] = (short)f2bf(f1.y);
        val[6] = (short)f2bf(f1.z); val[7] = (short)f2bf(f1.w);
        *(bf16x8*)(Aedge + row * ND + ((cc * 8) ^ ((row & 7) * 8))) = val;
    }
    __syncthreads();

    // ---- GEMM1: acc1(32x64 slice) = [src|dst|edge](64x384) @ W1 ----
    // wave (wm,wn): rows wm*32..+32, cols wn*64..+64
    f32x4 acc1[2][4];
    #pragma unroll
    for (int mt = 0; mt < 2; ++mt)
        #pragma unroll
        for (int nt = 0; nt < 4; ++nt)
            acc1[mt][nt] = (f32x4)0.0f;

    #pragma unroll
    for (int ks = 0; ks < 12; ++ks) {
        const unsigned short* Ab = (ks < 4) ? Asrc : (ks < 8 ? Adst : Aedge);
        int c0 = (ks & 3) * 32 + lhi * 8;     // k-offset within the 128-col block
        bf16x8 a[2];
        #pragma unroll
        for (int mt = 0; mt < 2; ++mt) {
            int row = wm * 32 + mt * 16 + l15;
            a[mt] = *(const bf16x8*)(Ab + row * ND + (c0 ^ ((row & 7) * 8)));
        }
        #pragma unroll
        for (int nt = 0; nt < 4; ++nt) {
            int n = wn * 64 + nt * 16 + l15;
            bf16x8 b = *(const bf16x8*)(w1t + (size_t)n * IND + ks * 32 + lhi * 8);
            #pragma unroll
            for (int mt = 0; mt < 2; ++mt)
                acc1[mt][nt] = __builtin_amdgcn_mfma_f32_16x16x32_bf16(a[mt], b, acc1[mt][nt], 0, 0, 0);
        }
    }
    __syncthreads();   // all GEMM1 A-reads done before Hs overlays Asrc/Adst

    // ---- merge: Hs = relu(acc1 + b1) (overlays Asrc+Adst; Aedge untouched) ----
    #pragma unroll
    for (int nt = 0; nt < 4; ++nt) {
        int col = wn * 64 + nt * 16 + l15;
        float bias = b1[col];
        #pragma unroll
        for (int mt = 0; mt < 2; ++mt) {
            #pragma unroll
            for (int r = 0; r < 4; ++r) {
                int row = wm * 32 + mt * 16 + lhi * 4 + r;
                float v = acc1[mt][nt][r] + bias;
                v = v > 0.0f ? v : 0.0f;
                Hs[row * HID + (col ^ ((row & 7) * 8))] = f2bf(v);
            }
        }
    }
    __syncthreads();

    // ---- GEMM2: acc2(32x32 slice) = Hs(64x256) @ W2 ----
    // wave (wm,wn): rows wm*32..+32, cols wn*32..+32
    f32x4 acc2[2][2];
    #pragma unroll
    for (int mt = 0; mt < 2; ++mt)
        #pragma unroll
        for (int nt = 0; nt < 2; ++nt)
            acc2[mt][nt] = (f32x4)0.0f;

    #pragma unroll
    for (int ks = 0; ks < 8; ++ks) {
        int c0 = ks * 32 + lhi * 8;
        bf16x8 a[2];
        #pragma unroll
        for (int mt = 0; mt < 2; ++mt) {
            int row = wm * 32 + mt * 16 + l15;
            a[mt] = *(const bf16x8*)(Hs + row * HID + (c0 ^ ((row & 7) * 8)));
        }
        #pragma unroll
        for (int nt = 0; nt < 2; ++nt) {
            int n = wn * 32 + nt * 16 + l15;
            bf16x8 b = *(const bf16x8*)(w2t + (size_t)n * HID + c0);
            #pragma unroll
            for (int mt = 0; mt < 2; ++mt)
                acc2[mt][nt] = __builtin_amdgcn_mfma_f32_16x16x32_bf16(a[mt], b, acc2[mt][nt], 0, 0, 0);
        }
    }

    // ---- epilogue: out = Aedge(bf16 edge) + update + b2 ----
    #pragma unroll
    for (int nt = 0; nt < 2; ++nt) {
        int col = wn * 32 + nt * 16 + l15;    // 0..127
        float bias = b2[col];
        #pragma unroll
        for (int mt = 0; mt < 2; ++mt) {
            #pragma unroll
            for (int r = 0; r < 4; ++r) {
                int row = wm * 32 + mt * 16 + lhi * 4 + r;
                int e = base + row;
                if (e < E_TOTAL) {
                    float ev = bf2f(Aedge[row * ND + (col ^ ((row & 7) * 8))]);
                    out[(size_t)e * ED + col] = ev + acc2[mt][nt][r] + bias;
                }
            }
        }
    }
}

extern "C" void kernel_launch(void* const* d_in, const int* in_sizes, int n_in,
                              void* d_out, int out_size, void* d_ws, size_t ws_size,
                              hipStream_t stream) {
    const float* nf   = (const float*)d_in[0];
    const float* ef   = (const float*)d_in[1];
    const int*   eidx = (const int*)d_in[2];
    const float* W1   = (const float*)d_in[3];
    const float* b1   = (const float*)d_in[4];
    const float* W2   = (const float*)d_in[5];
    const float* b2   = (const float*)d_in[6];
    float* out = (float*)d_out;

    unsigned short* nodesb = (unsigned short*)d_ws;        // 12.8 MB
    unsigned short* w1t    = nodesb + (size_t)NN * ND;     // 192 KB
    unsigned short* w2t    = w1t + IND * HID;              // 64 KB

    int wtotal = IND * HID + HID * ED;
    prep_nodes<<<(NN * ND / 4 + 255) / 256, 256, 0, stream>>>(nf, nodesb);
    prep_weights<<<(wtotal + 255) / 256, 256, 0, stream>>>(W1, W2, w1t, w2t);
    edge_mlp<<<NBLOCKS, 512, 0, stream>>>(ef, eidx, nodesb, w1t, w2t, b1, b2, out);
}